// Round 3
// baseline (499.716 us; speedup 1.0000x reference)
//
#include <hip/hip_runtime.h>
#include <math.h>

// Problem geometry (fixed by the reference setup_inputs()).
#define HH 512
#define WW 512
#define BATCH 8
#define PIX (HH * WW)            // 262144 pixels per image
#define NCH 16                   // 8 pred channels + 8 target channels (fused skeletonize)
#define NPIX_TOT (NCH * PIX)     // 4,194,304
#define N_ELEM (BATCH * PIX)     // 2,097,152 elements per (8,1,512,512) tensor
#define EPSV 1e-6

// Fused 2-iteration skeletonize tile geometry.
#define TS 64                    // output tile is TS x TS
#define AW 70                    // img tile width, halo 3 (2 iters fused)
#define E1W 68                   // erode-1 tile width, halo 2
// final (1-iter) kernel geometry
#define FIW 68                   // img halo 2
#define FEW 66                   // erode halo 1

// Accumulator layout (doubles at ws[0]):
//  [0..7]   dice-mask inter | [8..15] sum p | [16..23] sum m        (per batch)
//  [24..31] dice-skel inter | [32..39] sum q | [40..47] sum s       (per batch)
//  [48] focal-mask  [49] focal-junc  [50] focal-endp
//  [51] smooth-L1   [52] uncertainty MSE
//  [53..60] cldice sum ps*mask  [61..68] sum ps
//  [69..76] cldice sum ts*p     [77..84] sum ts
#define ACC_COUNT 128
#define ACC_BYTES (ACC_COUNT * sizeof(double))
#define NPART 12                 // partials per block (11 used, padded)

__device__ __forceinline__ float sigm(float x) {
    return __fdividef(1.0f, 1.0f + __expf(-x));
}
__device__ __forceinline__ float clamp01(float v) { return fminf(fmaxf(v, 0.0f), 1.0f); }

// bce = max(x,0) - x*t + log1p(exp(-|x|));  log1p(exp(-|x|)) = -log(max(p,1-p))
__device__ __forceinline__ float focal_term(float x, float t, float p) {
    float bce = fmaxf(x, 0.0f) - x * t - __logf(fmaxf(p, 1.0f - p));
    float p_t = p * t + (1.0f - p) * (1.0f - t);
    float a_t = 0.25f * t + 0.75f * (1.0f - t);
    float om  = 1.0f - p_t;
    return a_t * om * om * bce;
}

// Block (256 threads) sum reduction in double; result valid on thread 0.
__device__ __forceinline__ double blockReduceSum(double v, double* sm4) {
    int lane = threadIdx.x & 63, wid = threadIdx.x >> 6;
#pragma unroll
    for (int off = 32; off; off >>= 1) v += __shfl_down(v, off);
    __syncthreads();                 // protect sm4 reuse across successive calls
    if (lane == 0) sm4[wid] = v;
    __syncthreads();
    double r = 0.0;
    if (threadIdx.x == 0) r = sm4[0] + sm4[1] + sm4[2] + sm4[3];
    return r;
}

// ---------------------------------------------------------------------------
// K1: all point-wise losses that don't need the skeletons.
// 1024 blocks (128/batch); each thread: 8 px via 2 float4 rounds per array.
// No atomics: per-block partials -> part[block*12 + q].
// ---------------------------------------------------------------------------
__global__ __launch_bounds__(256) void k_main_reduce(
    const float* __restrict__ mask_logits, const float* __restrict__ skel_logits,
    const float* __restrict__ unc_logits,  const float* __restrict__ junc_logits,
    const float* __restrict__ endp_logits, const float* __restrict__ aff_pred,
    const float* __restrict__ mask,        const float* __restrict__ skel,
    const float* __restrict__ junc,        const float* __restrict__ endp,
    const float* __restrict__ aff_tgt,     const float* __restrict__ unc,
    double* __restrict__ part)
{
    __shared__ double sm4[4];
    const int b    = blockIdx.x >> 7;          // batch index
    const int pix0 = (blockIdx.x & 127) * 2048;

    float q0 = 0, q1 = 0, q2 = 0, q3 = 0, q4 = 0, q5 = 0;
    float q6 = 0, q7 = 0, q8 = 0, q9 = 0, q10 = 0;

#pragma unroll 1
    for (int r = 0; r < 2; ++r) {
        const int pix = pix0 + r * 1024 + threadIdx.x * 4;
        const int i   = b * PIX + pix;

        float4 ml = *(const float4*)&mask_logits[i];
        float4 mm = *(const float4*)&mask[i];
        float4 sl = *(const float4*)&skel_logits[i];
        float4 ss = *(const float4*)&skel[i];
        float4 jl = *(const float4*)&junc_logits[i];
        float4 jt = *(const float4*)&junc[i];
        float4 el = *(const float4*)&endp_logits[i];
        float4 et = *(const float4*)&endp[i];
        float4 ul = *(const float4*)&unc_logits[i];
        float4 ut = *(const float4*)&unc[i];
        float4 a0 = *(const float4*)&aff_pred[(b * 2 + 0) * PIX + pix];
        float4 t0 = *(const float4*)&aff_tgt [(b * 2 + 0) * PIX + pix];
        float4 a1 = *(const float4*)&aff_pred[(b * 2 + 1) * PIX + pix];
        float4 t1 = *(const float4*)&aff_tgt [(b * 2 + 1) * PIX + pix];

        const float* mlv = (const float*)&ml; const float* mmv = (const float*)&mm;
        const float* slv = (const float*)&sl; const float* ssv = (const float*)&ss;
        const float* jlv = (const float*)&jl; const float* jtv = (const float*)&jt;
        const float* elv = (const float*)&el; const float* etv = (const float*)&et;
        const float* ulv = (const float*)&ul; const float* utv = (const float*)&ut;
        const float* a0v = (const float*)&a0; const float* t0v = (const float*)&t0;
        const float* a1v = (const float*)&a1; const float* t1v = (const float*)&t1;

#pragma unroll
        for (int k = 0; k < 4; ++k) {
            float x = mlv[k], m = mmv[k];
            float p = sigm(x);
            q0 += p * m; q1 += p; q2 += m;
            q6 += focal_term(x, m, p);

            float sx = slv[k], s = ssv[k];
            float sp = sigm(sx);
            q3 += sp * s; q4 += sp; q5 += s;

            float jx = jlv[k];
            q7 += focal_term(jx, jtv[k], sigm(jx));
            float ex = elv[k];
            q8 += focal_term(ex, etv[k], sigm(ex));

            float ud = sigm(ulv[k]) - utv[k];
            q10 += ud * ud;

            float d0 = a0v[k] * s - t0v[k] * s;
            float ad0 = fabsf(d0);
            q9 += (ad0 < 1.0f) ? 0.5f * d0 * d0 : ad0 - 0.5f;
            float d1 = a1v[k] * s - t1v[k] * s;
            float ad1 = fabsf(d1);
            q9 += (ad1 < 1.0f) ? 0.5f * d1 * d1 : ad1 - 0.5f;
        }
    }

    double* p = &part[blockIdx.x * NPART];
    double r;
    r = blockReduceSum((double)q0, sm4);  if (threadIdx.x == 0) p[0]  = r;
    r = blockReduceSum((double)q1, sm4);  if (threadIdx.x == 0) p[1]  = r;
    r = blockReduceSum((double)q2, sm4);  if (threadIdx.x == 0) p[2]  = r;
    r = blockReduceSum((double)q3, sm4);  if (threadIdx.x == 0) p[3]  = r;
    r = blockReduceSum((double)q4, sm4);  if (threadIdx.x == 0) p[4]  = r;
    r = blockReduceSum((double)q5, sm4);  if (threadIdx.x == 0) p[5]  = r;
    r = blockReduceSum((double)q6, sm4);  if (threadIdx.x == 0) p[6]  = r;
    r = blockReduceSum((double)q7, sm4);  if (threadIdx.x == 0) p[7]  = r;
    r = blockReduceSum((double)q8, sm4);  if (threadIdx.x == 0) p[8]  = r;
    r = blockReduceSum((double)q9, sm4);  if (threadIdx.x == 0) p[9]  = r;
    r = blockReduceSum((double)q10, sm4); if (threadIdx.x == 0) p[10] = r;
}

// ---------------------------------------------------------------------------
// Combine per-block partials into acc[0..52]. 1 block, 256 threads (4 waves).
// Tasks 0..47: per-batch group g (0..5) x batch b: sum 128 block-partials.
// Tasks 48..52: scalar quantities q6..q10: sum 1024 block-partials.
// ---------------------------------------------------------------------------
__global__ __launch_bounds__(256) void k_combine(
    const double* __restrict__ part, double* __restrict__ acc)
{
    const int wave = threadIdx.x >> 6, lane = threadIdx.x & 63;
    for (int T = wave; T < 53; T += 4) {
        double v = 0.0;
        if (T < 48) {
            int g = T >> 3, b = T & 7;
            int blk = b * 128 + lane * 2;
            v = part[blk * NPART + g] + part[(blk + 1) * NPART + g];
        } else {
            int q = 6 + (T - 48);
#pragma unroll
            for (int i = 0; i < 16; ++i) v += part[(lane + 64 * i) * NPART + q];
        }
#pragma unroll
        for (int off = 32; off; off >>= 1) v += __shfl_down(v, off);
        if (lane == 0) {
            if (T < 48) acc[(T >> 3) * 8 + (T & 7)] = v;
            else        acc[48 + (T - 48)] = v;
        }
    }
}

// ---------------------------------------------------------------------------
// Fused DOUBLE skeletonize iteration: performs updates {k, k+1} and writes
// img_{k+2}. One block = one 64x64 tile of one channel.
//   sA: img tile halo 3 (+inf OOB)  -> later reused for E2 (halo 1, -inf OOB)
//   sE: E1 = erode(img), halo 2 (-inf at OOB positions)
// Skeleton state is carried in 16 registers/thread: read once, written once.
// MODE 0 (init): img = clip(sigmoid(logits)) / clip(mask); sk starts at delta0.
// MODE 1 (mid):  img from buffer; sk read from global.
// ---------------------------------------------------------------------------
template<int MODE>
__global__ __launch_bounds__(256) void k_skel2(
    const float* __restrict__ in0,    // MODE 0: mask_logits ; MODE 1: img in
    const float* __restrict__ in1,    // MODE 0: mask
    float* __restrict__ outImg,       // img_{k+2}
    float* __restrict__ skel)
{
    __shared__ float sA[AW * AW];     // 70*70*4 = 19.6 KB
    __shared__ float sE[E1W * E1W];   // 68*68*4 = 18.5 KB

    const int c    = blockIdx.x >> 6;        // channel 0..15
    const int tile = blockIdx.x & 63;
    const int by   = (tile >> 3) * TS;
    const int bx   = (tile & 7) * TS;

    // Phase 1: img tile (halo 3), +inf outside image
    for (int idx = threadIdx.x; idx < AW * AW; idx += 256) {
        int ly = idx / AW, lx = idx - ly * AW;
        int gy = by - 3 + ly, gx = bx - 3 + lx;
        float v = INFINITY;
        if (gy >= 0 && gy < HH && gx >= 0 && gx < WW) {
            int gi = (gy << 9) + gx;
            if (MODE == 0)
                v = (c < 8) ? clamp01(sigm(in0[c * PIX + gi]))
                            : clamp01(in1[(c - 8) * PIX + gi]);
            else
                v = in0[c * PIX + gi];
        }
        sA[idx] = v;
    }
    __syncthreads();

    // Phase 2: E1 = erode(img) over halo-2 region; -inf at OOB positions
    for (int idx = threadIdx.x; idx < E1W * E1W; idx += 256) {
        int ey = idx / E1W, ex = idx - ey * E1W;
        int gy = by - 2 + ey, gx = bx - 2 + ex;
        float e = -INFINITY;
        if (gy >= 0 && gy < HH && gx >= 0 && gx < WW) {
            int ci = (ey + 1) * AW + (ex + 1);
            float v = sA[ci];
            v = fminf(v, sA[ci - AW]); v = fminf(v, sA[ci + AW]);
            v = fminf(v, sA[ci - 1]);  v = fminf(v, sA[ci + 1]);
            e = v;
        }
        sE[idx] = e;
    }
    __syncthreads();

    // Phase 3: update k (delta0 from img center & max3(E1)); sk into registers
    float sk[16];
#pragma unroll
    for (int j = 0; j < 16; ++j) {
        int idx = j * 256 + threadIdx.x;
        int oy = idx >> 6, ox = idx & 63;
        int c1 = (oy + 2) * E1W + (ox + 2);
        float mx = sE[c1 - E1W - 1];
        mx = fmaxf(mx, sE[c1 - E1W]);     mx = fmaxf(mx, sE[c1 - E1W + 1]);
        mx = fmaxf(mx, sE[c1 - 1]);       mx = fmaxf(mx, sE[c1]);
        mx = fmaxf(mx, sE[c1 + 1]);       mx = fmaxf(mx, sE[c1 + E1W - 1]);
        mx = fmaxf(mx, sE[c1 + E1W]);     mx = fmaxf(mx, sE[c1 + E1W + 1]);
        float img = sA[(oy + 3) * AW + (ox + 3)];
        float d0  = fmaxf(img - mx, 0.0f);
        if (MODE == 0) {
            sk[j] = d0;
        } else {
            int gi = c * PIX + ((by + oy) << 9) + (bx + ox);
            float s = skel[gi];
            sk[j] = s + fmaxf(d0 - s * d0, 0.0f);
        }
    }
    __syncthreads();   // all sA(img) reads done before overwrite with E2

    // Phase 4: E2 = erode(E1) over halo-1 region, into sA (stride AW).
    // E1 holds -inf at OOB, so guard each neighbor by image bounds (+inf skip).
    for (int idx = threadIdx.x; idx < 66 * 66; idx += 256) {
        int ey = idx / 66, ex = idx - ey * 66;
        int gy = by - 1 + ey, gx = bx - 1 + ex;
        float e = -INFINITY;
        if (gy >= 0 && gy < HH && gx >= 0 && gx < WW) {
            int ci = (ey + 1) * E1W + (ex + 1);
            float v = sE[ci];
            if (gy > 0)      v = fminf(v, sE[ci - E1W]);
            if (gy < HH - 1) v = fminf(v, sE[ci + E1W]);
            if (gx > 0)      v = fminf(v, sE[ci - 1]);
            if (gx < WW - 1) v = fminf(v, sE[ci + 1]);
            e = v;
        }
        sA[ey * AW + ex] = e;
    }
    __syncthreads();

    // Phase 5: update k+1 (delta1 from E1 center & max3(E2)); write sk + img out
#pragma unroll
    for (int j = 0; j < 16; ++j) {
        int idx = j * 256 + threadIdx.x;
        int oy = idx >> 6, ox = idx & 63;
        int c2 = (oy + 1) * AW + (ox + 1);
        float mx = sA[c2 - AW - 1];
        mx = fmaxf(mx, sA[c2 - AW]);     mx = fmaxf(mx, sA[c2 - AW + 1]);
        mx = fmaxf(mx, sA[c2 - 1]);      mx = fmaxf(mx, sA[c2]);
        mx = fmaxf(mx, sA[c2 + 1]);      mx = fmaxf(mx, sA[c2 + AW - 1]);
        mx = fmaxf(mx, sA[c2 + AW]);     mx = fmaxf(mx, sA[c2 + AW + 1]);
        float e1c = sE[(oy + 2) * E1W + (ox + 2)];
        float d1  = fmaxf(e1c - mx, 0.0f);
        float s   = sk[j];
        s = s + fmaxf(d1 - s * d1, 0.0f);
        int gi = c * PIX + ((by + oy) << 9) + (bx + ox);
        skel[gi]   = s;
        outImg[gi] = sA[c2];             // E2 center = img_{k+2}
    }
}

// ---------------------------------------------------------------------------
// Final skeletonize iteration (update 10) + cldice partial sums. No writes.
// ---------------------------------------------------------------------------
__global__ __launch_bounds__(256) void k_skel_final(
    const float* __restrict__ img,          // img_10
    const float* __restrict__ mask_logits,
    const float* __restrict__ mask,
    const float* __restrict__ skel,
    double* __restrict__ acc)
{
    __shared__ float simg[FIW * FIW];  // halo 2
    __shared__ float sE[FEW * FIW];    // halo 1, stride FIW
    __shared__ double sm4[4];

    const int c    = blockIdx.x >> 6;
    const int tile = blockIdx.x & 63;
    const int by   = (tile >> 3) * TS;
    const int bx   = (tile & 7) * TS;

    for (int idx = threadIdx.x; idx < FIW * FIW; idx += 256) {
        int ly = idx / FIW, lx = idx - ly * FIW;
        int gy = by - 2 + ly, gx = bx - 2 + lx;
        float v = INFINITY;
        if (gy >= 0 && gy < HH && gx >= 0 && gx < WW)
            v = img[c * PIX + (gy << 9) + gx];
        simg[idx] = v;
    }
    __syncthreads();

    for (int idx = threadIdx.x; idx < FEW * FEW; idx += 256) {
        int ey = idx / FEW, ex = idx - ey * FEW;
        int gy = by - 1 + ey, gx = bx - 1 + ex;
        float e = -INFINITY;
        if (gy >= 0 && gy < HH && gx >= 0 && gx < WW) {
            int ci = (ey + 1) * FIW + (ex + 1);
            float v = simg[ci];
            v = fminf(v, simg[ci - FIW]); v = fminf(v, simg[ci + FIW]);
            v = fminf(v, simg[ci - 1]);   v = fminf(v, simg[ci + 1]);
            e = v;
        }
        sE[ey * FIW + ex] = e;
    }
    __syncthreads();

    double t0 = 0.0, t1 = 0.0;
    for (int idx = threadIdx.x; idx < TS * TS; idx += 256) {
        int oy = idx >> 6, ox = idx & 63;
        int gy = by + oy, gx = bx + ox;
        int eci = (oy + 1) * FIW + (ox + 1);

        float mx = sE[eci - FIW - 1];
        mx = fmaxf(mx, sE[eci - FIW]);   mx = fmaxf(mx, sE[eci - FIW + 1]);
        mx = fmaxf(mx, sE[eci - 1]);     mx = fmaxf(mx, sE[eci]);
        mx = fmaxf(mx, sE[eci + 1]);     mx = fmaxf(mx, sE[eci + FIW - 1]);
        mx = fmaxf(mx, sE[eci + FIW]);   mx = fmaxf(mx, sE[eci + FIW + 1]);

        float im    = simg[(oy + 2) * FIW + (ox + 2)];
        float delta = fmaxf(im - mx, 0.0f);

        int gi   = c * PIX + (gy << 9) + gx;
        float s0 = skel[gi];
        float ns = clamp01(s0 + fmaxf(delta - s0 * delta, 0.0f));  // final clip

        int pi = (gy << 9) + gx;
        if (c < 8) {            // pred skeleton vs target mask (precision sums)
            float m = mask[c * PIX + pi];
            t0 += (double)(ns * m);  t1 += (double)ns;
        } else {                // target skeleton vs pred probs (sensitivity)
            float p = sigm(mask_logits[(c - 8) * PIX + pi]);
            t0 += (double)(ns * p);  t1 += (double)ns;
        }
    }

    double r0 = blockReduceSum(t0, sm4);
    double r1 = blockReduceSum(t1, sm4);
    if (threadIdx.x == 0) {
        if (c < 8) { atomicAdd(&acc[53 + c], r0);     atomicAdd(&acc[61 + c], r1); }
        else       { atomicAdd(&acc[69 + c - 8], r0); atomicAdd(&acc[77 + c - 8], r1); }
    }
}

// ---------------------------------------------------------------------------
// Combine everything into the scalar loss.
// ---------------------------------------------------------------------------
__global__ void k_finalize(const double* __restrict__ acc, float* __restrict__ out)
{
    if (threadIdx.x != 0 || blockIdx.x != 0) return;
    const double eps = EPSV;
    const double Nd  = (double)N_ELEM;

    double dm = 0, ds = 0, cl = 0, msum = 0;
    for (int b = 0; b < BATCH; ++b) {
        dm += (2.0 * acc[0 + b] + eps) / (acc[8 + b] + acc[16 + b] + eps);
        ds += (2.0 * acc[24 + b] + eps) / (acc[32 + b] + acc[40 + b] + eps);
        double prec = acc[53 + b] / (acc[61 + b] + eps);
        double sens = acc[69 + b] / (acc[77 + b] + eps);
        cl += (2.0 * prec * sens + eps) / (prec + sens + eps);
        msum += acc[40 + b];
    }
    msum *= 2.0;   // skeleton mask broadcast over 2 affinity channels

    double mask_loss = (1.0 - dm / 8.0) + acc[48] / Nd;
    double skel_loss = 1.0 - ds / 8.0;
    double topo      = 1.0 - cl / 8.0;
    double node      = 0.5 * (acc[49] / Nd + acc[50] / Nd);
    double aff       = (msum == 0.0) ? 0.0 : acc[51] / fmax(msum, 1.0);
    double unc       = acc[52] / Nd;

    double total = mask_loss + skel_loss + 0.5 * topo + 0.5 * node + 0.5 * aff + 0.1 * unc;
    out[0] = (float)total;
}

// ---------------------------------------------------------------------------
extern "C" void kernel_launch(void* const* d_in, const int* in_sizes, int n_in,
                              void* d_out, int out_size, void* d_ws, size_t ws_size,
                              hipStream_t stream)
{
    const float* mask_logits = (const float*)d_in[0];
    const float* skel_logits = (const float*)d_in[1];
    const float* unc_logits  = (const float*)d_in[2];
    const float* junc_logits = (const float*)d_in[3];
    const float* endp_logits = (const float*)d_in[4];
    const float* aff_pred    = (const float*)d_in[5];
    const float* mask        = (const float*)d_in[6];
    const float* skel        = (const float*)d_in[7];
    const float* junc        = (const float*)d_in[8];
    const float* endp        = (const float*)d_in[9];
    const float* aff_tgt     = (const float*)d_in[10];
    const float* unc         = (const float*)d_in[11];
    float* out = (float*)d_out;

    char* ws = (char*)d_ws;
    double* acc = (double*)ws;
    float* P0   = (float*)(ws + ACC_BYTES);
    float* P1   = P0 + NPIX_TOT;
    float* SKEL = P1 + NPIX_TOT;
    // Partials alias the start of P0: consumed by k_combine BEFORE any kernel
    // writes P0 (first P0 write is the 2nd k_skel2 dispatch).
    double* part = (double*)P0;   // 1024 * 12 doubles = 96 KB << 16 MB
    // total ws usage: 1 KiB + 3 * 16 MiB (same as the previously-passing layout)

    hipMemsetAsync(acc, 0, ACC_BYTES, stream);

    k_main_reduce<<<1024, 256, 0, stream>>>(
        mask_logits, skel_logits, unc_logits, junc_logits, endp_logits,
        aff_pred, mask, skel, junc, endp, aff_tgt, unc, part);
    k_combine<<<1, 256, 0, stream>>>(part, acc);

    const int SGRID = NCH * 64;  // 1024 blocks: 16 channels x (8x8 tiles)

    // updates 0,1 -> img_2 in P1 ; skeleton initialized
    k_skel2<0><<<SGRID, 256, 0, stream>>>(mask_logits, mask, P1, SKEL);
    // updates 2..9 -> img_4, img_6, img_8, img_10 (P0/P1 ping-pong)
    k_skel2<1><<<SGRID, 256, 0, stream>>>(P1, nullptr, P0, SKEL);
    k_skel2<1><<<SGRID, 256, 0, stream>>>(P0, nullptr, P1, SKEL);
    k_skel2<1><<<SGRID, 256, 0, stream>>>(P1, nullptr, P0, SKEL);
    k_skel2<1><<<SGRID, 256, 0, stream>>>(P0, nullptr, P1, SKEL);
    // update 10 + cldice sums (no writes)
    k_skel_final<<<SGRID, 256, 0, stream>>>(P1, mask_logits, mask, SKEL, acc);

    k_finalize<<<1, 64, 0, stream>>>(acc, out);
}

// Round 4
// 243.894 us; speedup vs baseline: 2.0489x; 2.0489x over previous
//
#include <hip/hip_runtime.h>
#include <math.h>

// Problem geometry (fixed by the reference setup_inputs()).
#define HH 512
#define WW 512
#define BATCH 8
#define PIX (HH * WW)            // 262144 pixels per image
#define NCH 16                   // 8 pred + 8 target channels (fused skeletonize)
#define NPIX_TOT (NCH * PIX)
#define N_ELEM (BATCH * PIX)
#define EPSV 1e-6

// Accumulator layout (doubles at ws[0]):
//  [0..7] dice-mask inter | [8..15] sum p | [16..23] sum m       (per batch)
//  [24..31] dice-skel inter | [32..39] sum q | [40..47] sum s    (per batch)
//  [48] focal-mask [49] focal-junc [50] focal-endp [51] smoothL1 [52] unc-MSE
//  [53..60] cldice sum ps*mask  [61..68] sum ps
//  [69..76] cldice sum ts*p     [77..84] sum ts
#define ACC_COUNT 128
#define ACC_BYTES (ACC_COUNT * sizeof(double))
#define NPART 12
#define MRB 2048                 // main-reduce blocks

__device__ __forceinline__ float sigm(float x) {
    return __fdividef(1.0f, 1.0f + __expf(-x));
}
__device__ __forceinline__ float clamp01(float v) { return fminf(fmaxf(v, 0.0f), 1.0f); }

__device__ __forceinline__ float focal_term(float x, float t, float p) {
    float bce = fmaxf(x, 0.0f) - x * t - __logf(fmaxf(p, 1.0f - p));
    float p_t = p * t + (1.0f - p) * (1.0f - t);
    float a_t = 0.25f * t + 0.75f * (1.0f - t);
    float om  = 1.0f - p_t;
    return a_t * om * om * bce;
}

__device__ __forceinline__ double blockReduceSum(double v, double* sm4) {
    int lane = threadIdx.x & 63, wid = threadIdx.x >> 6;
#pragma unroll
    for (int off = 32; off; off >>= 1) v += __shfl_down(v, off);
    __syncthreads();
    if (lane == 0) sm4[wid] = v;
    __syncthreads();
    double r = 0.0;
    if (threadIdx.x == 0) r = sm4[0] + sm4[1] + sm4[2] + sm4[3];
    return r;
}

// ---------------------------------------------------------------------------
// float4 / 8-wide row helpers
// ---------------------------------------------------------------------------
struct F8 { float4 a, b; };

__device__ __forceinline__ float4 f4min(float4 x, float4 y) {
    return make_float4(fminf(x.x,y.x), fminf(x.y,y.y), fminf(x.z,y.z), fminf(x.w,y.w));
}
__device__ __forceinline__ float4 f4max(float4 x, float4 y) {
    return make_float4(fmaxf(x.x,y.x), fmaxf(x.y,y.y), fmaxf(x.z,y.z), fmaxf(x.w,y.w));
}
__device__ __forceinline__ F8 f8min(F8 x, F8 y) { F8 r; r.a=f4min(x.a,y.a); r.b=f4min(x.b,y.b); return r; }
__device__ __forceinline__ F8 f8max(F8 x, F8 y) { F8 r; r.a=f4max(x.a,y.a); r.b=f4max(x.b,y.b); return r; }
__device__ __forceinline__ F8 f8const(float v) {
    F8 r; r.a = make_float4(v,v,v,v); r.b = r.a; return r;
}
__device__ __forceinline__ F8 f8sigm(F8 x) {
    F8 r;
    r.a = make_float4(sigm(x.a.x), sigm(x.a.y), sigm(x.a.z), sigm(x.a.w));
    r.b = make_float4(sigm(x.b.x), sigm(x.b.y), sigm(x.b.z), sigm(x.b.w));
    return r;
}
__device__ __forceinline__ F8 f8clamp01(F8 x) {
    F8 r;
    r.a = make_float4(clamp01(x.a.x), clamp01(x.a.y), clamp01(x.a.z), clamp01(x.a.w));
    r.b = make_float4(clamp01(x.b.x), clamp01(x.b.y), clamp01(x.b.z), clamp01(x.b.w));
    return r;
}

// soft_erode on one row: min(center, up, down, left, right). Horizontal
// neighbors via in-register shifts + lane-edge shuffles (+inf at x-bounds).
__device__ __forceinline__ F8 erode_row(const F8& up, const F8& ce, const F8& dn, int lane) {
    F8 vm = f8min(f8min(up, dn), ce);
    float Lin = __shfl_up(ce.b.w, 1);
    float Rin = __shfl_down(ce.a.x, 1);
    if (lane == 0)  Lin = INFINITY;
    if (lane == 63) Rin = INFINITY;
    float4 la = make_float4(Lin,    ce.a.x, ce.a.y, ce.a.z);
    float4 lb = make_float4(ce.a.w, ce.b.x, ce.b.y, ce.b.z);
    float4 ra = make_float4(ce.a.y, ce.a.z, ce.a.w, ce.b.x);
    float4 rb = make_float4(ce.b.y, ce.b.z, ce.b.w, Rin);
    F8 r;
    r.a = f4min(vm.a, f4min(la, ra));
    r.b = f4min(vm.b, f4min(lb, rb));
    return r;
}

// 3x3 max of E at one row: separable (vertical max3 then horizontal max3,
// -inf at x-bounds).
__device__ __forceinline__ F8 max3_row(const F8& u, const F8& c, const F8& d, int lane) {
    F8 vm = f8max(f8max(u, d), c);
    float Lin = __shfl_up(vm.b.w, 1);
    float Rin = __shfl_down(vm.a.x, 1);
    if (lane == 0)  Lin = -INFINITY;
    if (lane == 63) Rin = -INFINITY;
    float4 la = make_float4(Lin,    vm.a.x, vm.a.y, vm.a.z);
    float4 lb = make_float4(vm.a.w, vm.b.x, vm.b.y, vm.b.z);
    float4 ra = make_float4(vm.a.y, vm.a.z, vm.a.w, vm.b.x);
    float4 rb = make_float4(vm.b.y, vm.b.z, vm.b.w, Rin);
    F8 r;
    r.a = f4max(vm.a, f4max(la, ra));
    r.b = f4max(vm.b, f4max(lb, rb));
    return r;
}

// t *= (1 - relu(img - mx))   [skel = 1 - t identity for the additive update]
__device__ __forceinline__ float4 f4updt(float4 t, float4 im, float4 mx) {
    return make_float4(t.x * (1.0f - fmaxf(im.x - mx.x, 0.0f)),
                       t.y * (1.0f - fmaxf(im.y - mx.y, 0.0f)),
                       t.z * (1.0f - fmaxf(im.z - mx.z, 0.0f)),
                       t.w * (1.0f - fmaxf(im.w - mx.w, 0.0f)));
}

// ---------------------------------------------------------------------------
// Row-register soft-skeletonize engine.
// Grid: 16 channels x 32 strips = 512 blocks x 256 threads (4 waves).
// Strip outputs rows [S, S+16); block holds rows [S-8, S+24) (halo 8).
// Wave w owns held-local rows [8w, 8w+8); lane covers x in [8*lane, 8*lane+8)
// as two float4. Waves 1,2 own exactly the 16 center rows (t state + output).
// Per iteration: LDS-exchange 2 edge rows/side between waves, then rolling
// in-register erode + separable max3 + t update. Block-edge rows use +inf
// injection; validity shrinks 1 row/iter from the halo (8 >= ITERS+1).
// MODE 0 (A): load clip(sigmoid(logits))/clip(mask); run updates 0..ITERS-1;
//             write img_ITERS + t on center rows.
// MODE 1 (B): load img+t; run updates; then cldice partial sums (no writes).
// ---------------------------------------------------------------------------
template<int ITERS, int MODE>
__global__ __launch_bounds__(256, 2) void k_skel_engine(
    const float* __restrict__ srcA,   // MODE0: mask_logits ; MODE1: img buffer
    const float* __restrict__ srcB,   // MODE0: mask        ; MODE1: t buffer
    const float* __restrict__ mlg,    // MODE1: mask_logits (cldice, c>=8)
    const float* __restrict__ msk,    // MODE1: mask        (cldice, c<8)
    float* __restrict__ imgOut,       // MODE0
    float* __restrict__ tOut,         // MODE0
    double* __restrict__ acc)         // MODE1
{
    __shared__ float xbuf[4][4][WW];  // 32 KB: per-wave slots {row0,row1,row6,row7}
    __shared__ double sm4[4];

    const int tid   = threadIdx.x;
    const int lane  = tid & 63;
    const int w     = tid >> 6;
    const int c     = blockIdx.x >> 5;
    const int strip = blockIdx.x & 31;
    const int S     = strip * 16;
    const int grow0 = S - 8 + w * 8;
    const int x0    = lane * 8;
    const bool hasT = (w == 1 || w == 2);

    F8 img[8], t8[8];

    // ---- load held rows (+inf outside image) ----
#pragma unroll
    for (int j = 0; j < 8; ++j) {
        int g = grow0 + j;
        if (g < 0 || g >= HH) { img[j] = f8const(INFINITY); continue; }
        const float* base;
        if (MODE == 0) base = (c < 8) ? srcA + c * PIX : srcB + (c - 8) * PIX;
        else           base = srcA + c * PIX;
        const float* rp = base + (g << 9) + x0;
        F8 v; v.a = *(const float4*)rp; v.b = *(const float4*)(rp + 4);
        if (MODE == 0) v = (c < 8) ? f8sigm(v) : f8clamp01(v);
        img[j] = v;
    }
    if (MODE == 0) {
#pragma unroll
        for (int j = 0; j < 8; ++j) t8[j] = f8const(1.0f);
    } else {
        if (hasT) {
#pragma unroll
            for (int j = 0; j < 8; ++j) {
                const float* tp = srcB + c * PIX + ((grow0 + j) << 9) + x0;
                t8[j].a = *(const float4*)tp; t8[j].b = *(const float4*)(tp + 4);
            }
        } else {
#pragma unroll
            for (int j = 0; j < 8; ++j) t8[j] = f8const(1.0f);
        }
    }

    // ---- iterations ----
    for (int it = 0; it < ITERS; ++it) {
        __syncthreads();   // previous iteration's xbuf reads complete
        *(float4*)&xbuf[w][0][x0]     = img[0].a;
        *(float4*)&xbuf[w][0][x0 + 4] = img[0].b;
        *(float4*)&xbuf[w][1][x0]     = img[1].a;
        *(float4*)&xbuf[w][1][x0 + 4] = img[1].b;
        *(float4*)&xbuf[w][2][x0]     = img[6].a;
        *(float4*)&xbuf[w][2][x0 + 4] = img[6].b;
        *(float4*)&xbuf[w][3][x0]     = img[7].a;
        *(float4*)&xbuf[w][3][x0 + 4] = img[7].b;
        __syncthreads();

        F8 hU0, hU1, hD0, hD1;
        if (w > 0) {
            hU0.a = *(float4*)&xbuf[w-1][2][x0]; hU0.b = *(float4*)&xbuf[w-1][2][x0 + 4];
            hU1.a = *(float4*)&xbuf[w-1][3][x0]; hU1.b = *(float4*)&xbuf[w-1][3][x0 + 4];
        } else { hU0 = f8const(INFINITY); hU1 = f8const(INFINITY); }
        if (w < 3) {
            hD0.a = *(float4*)&xbuf[w+1][0][x0]; hD0.b = *(float4*)&xbuf[w+1][0][x0 + 4];
            hD1.a = *(float4*)&xbuf[w+1][1][x0]; hD1.b = *(float4*)&xbuf[w+1][1][x0 + 4];
        } else { hD0 = f8const(INFINITY); hD1 = f8const(INFINITY); }

        // rolling erode window: Em1 = E[local j-1], E0 = E[j], Ep1 = E[j+1]
        F8 Em1 = erode_row(hU0, hU1, img[0], lane);
        { int g = grow0 - 1; if (g < 0 || g >= HH) Em1 = f8const(-INFINITY); }
        F8 E0  = erode_row(hU1, img[0], img[1], lane);
        { int g = grow0;     if (g < 0 || g >= HH) E0  = f8const(-INFINITY); }

#pragma unroll
        for (int j = 0; j < 8; ++j) {
            F8 ce = (j < 7) ? img[j + 1] : hD0;
            F8 dn = (j < 6) ? img[j + 2] : ((j == 6) ? hD0 : hD1);
            F8 Ep1 = erode_row(img[j], ce, dn, lane);
            { int g = grow0 + j + 1; if (g < 0 || g >= HH) Ep1 = f8const(-INFINITY); }
            if (hasT) {
                F8 mx = max3_row(Em1, E0, Ep1, lane);
                t8[j].a = f4updt(t8[j].a, img[j].a, mx.a);
                t8[j].b = f4updt(t8[j].b, img[j].b, mx.b);
            }
            img[j] = E0;          // img becomes eroded image for next iteration
            Em1 = E0; E0 = Ep1;
        }
    }

    // ---- epilogue ----
    if (MODE == 0) {
        if (hasT) {
#pragma unroll
            for (int j = 0; j < 8; ++j) {
                int g = grow0 + j;
                float* ip = imgOut + c * PIX + (g << 9) + x0;
                *(float4*)ip       = img[j].a;
                *(float4*)(ip + 4) = img[j].b;
                float* tp = tOut + c * PIX + (g << 9) + x0;
                *(float4*)tp       = t8[j].a;
                *(float4*)(tp + 4) = t8[j].b;
            }
        }
    } else {
        double s0 = 0.0, s1 = 0.0;
        if (hasT) {
#pragma unroll
            for (int j = 0; j < 8; ++j) {
                int g = grow0 + j;
                const float* op = (c < 8) ? (msk + c * PIX + (g << 9) + x0)
                                          : (mlg + (c - 8) * PIX + (g << 9) + x0);
                F8 o; o.a = *(const float4*)op; o.b = *(const float4*)(op + 4);
                if (c >= 8) o = f8sigm(o);
                float ps0 = clamp01(1.0f - t8[j].a.x), ps1 = clamp01(1.0f - t8[j].a.y);
                float ps2 = clamp01(1.0f - t8[j].a.z), ps3 = clamp01(1.0f - t8[j].a.w);
                float ps4 = clamp01(1.0f - t8[j].b.x), ps5 = clamp01(1.0f - t8[j].b.y);
                float ps6 = clamp01(1.0f - t8[j].b.z), ps7 = clamp01(1.0f - t8[j].b.w);
                float rs = ((ps0 + ps1) + (ps2 + ps3)) + ((ps4 + ps5) + (ps6 + ps7));
                float rp = ((ps0 * o.a.x + ps1 * o.a.y) + (ps2 * o.a.z + ps3 * o.a.w))
                         + ((ps4 * o.b.x + ps5 * o.b.y) + (ps6 * o.b.z + ps7 * o.b.w));
                s1 += (double)rs;
                s0 += (double)rp;
            }
        }
        double r0 = blockReduceSum(s0, sm4);
        double r1 = blockReduceSum(s1, sm4);
        if (tid == 0) {
            if (c < 8) { atomicAdd(&acc[53 + c], r0);     atomicAdd(&acc[61 + c], r1); }
            else       { atomicAdd(&acc[69 + c - 8], r0); atomicAdd(&acc[77 + c - 8], r1); }
        }
    }
}

// ---------------------------------------------------------------------------
// K1: point-wise losses. 2048 blocks, 4 px/thread, one float4 round.
// ---------------------------------------------------------------------------
__global__ __launch_bounds__(256) void k_main_reduce(
    const float* __restrict__ mask_logits, const float* __restrict__ skel_logits,
    const float* __restrict__ unc_logits,  const float* __restrict__ junc_logits,
    const float* __restrict__ endp_logits, const float* __restrict__ aff_pred,
    const float* __restrict__ mask,        const float* __restrict__ skel,
    const float* __restrict__ junc,        const float* __restrict__ endp,
    const float* __restrict__ aff_tgt,     const float* __restrict__ unc,
    double* __restrict__ part)
{
    __shared__ double sm4[4];
    const int b   = blockIdx.x >> 8;
    const int pix = (blockIdx.x & 255) * 1024 + threadIdx.x * 4;
    const int i   = b * PIX + pix;

    float q0 = 0, q1 = 0, q2 = 0, q3 = 0, q4 = 0, q5 = 0;
    float q6 = 0, q7 = 0, q8 = 0, q9 = 0, q10 = 0;

    float4 ml = *(const float4*)&mask_logits[i];
    float4 mm = *(const float4*)&mask[i];
    float4 sl = *(const float4*)&skel_logits[i];
    float4 ss = *(const float4*)&skel[i];
    float4 jl = *(const float4*)&junc_logits[i];
    float4 jt = *(const float4*)&junc[i];
    float4 el = *(const float4*)&endp_logits[i];
    float4 et = *(const float4*)&endp[i];
    float4 ul = *(const float4*)&unc_logits[i];
    float4 ut = *(const float4*)&unc[i];
    float4 a0 = *(const float4*)&aff_pred[(b * 2 + 0) * PIX + pix];
    float4 t0 = *(const float4*)&aff_tgt [(b * 2 + 0) * PIX + pix];
    float4 a1 = *(const float4*)&aff_pred[(b * 2 + 1) * PIX + pix];
    float4 t1 = *(const float4*)&aff_tgt [(b * 2 + 1) * PIX + pix];

    const float* mlv = (const float*)&ml; const float* mmv = (const float*)&mm;
    const float* slv = (const float*)&sl; const float* ssv = (const float*)&ss;
    const float* jlv = (const float*)&jl; const float* jtv = (const float*)&jt;
    const float* elv = (const float*)&el; const float* etv = (const float*)&et;
    const float* ulv = (const float*)&ul; const float* utv = (const float*)&ut;
    const float* a0v = (const float*)&a0; const float* t0v = (const float*)&t0;
    const float* a1v = (const float*)&a1; const float* t1v = (const float*)&t1;

#pragma unroll
    for (int k = 0; k < 4; ++k) {
        float x = mlv[k], m = mmv[k];
        float p = sigm(x);
        q0 += p * m; q1 += p; q2 += m;
        q6 += focal_term(x, m, p);

        float sx = slv[k], s = ssv[k];
        float sp = sigm(sx);
        q3 += sp * s; q4 += sp; q5 += s;

        float jx = jlv[k];
        q7 += focal_term(jx, jtv[k], sigm(jx));
        float ex = elv[k];
        q8 += focal_term(ex, etv[k], sigm(ex));

        float ud = sigm(ulv[k]) - utv[k];
        q10 += ud * ud;

        float d0 = a0v[k] * s - t0v[k] * s;
        float ad0 = fabsf(d0);
        q9 += (ad0 < 1.0f) ? 0.5f * d0 * d0 : ad0 - 0.5f;
        float d1 = a1v[k] * s - t1v[k] * s;
        float ad1 = fabsf(d1);
        q9 += (ad1 < 1.0f) ? 0.5f * d1 * d1 : ad1 - 0.5f;
    }

    double* p = &part[blockIdx.x * NPART];
    double r;
    r = blockReduceSum((double)q0, sm4);  if (threadIdx.x == 0) p[0]  = r;
    r = blockReduceSum((double)q1, sm4);  if (threadIdx.x == 0) p[1]  = r;
    r = blockReduceSum((double)q2, sm4);  if (threadIdx.x == 0) p[2]  = r;
    r = blockReduceSum((double)q3, sm4);  if (threadIdx.x == 0) p[3]  = r;
    r = blockReduceSum((double)q4, sm4);  if (threadIdx.x == 0) p[4]  = r;
    r = blockReduceSum((double)q5, sm4);  if (threadIdx.x == 0) p[5]  = r;
    r = blockReduceSum((double)q6, sm4);  if (threadIdx.x == 0) p[6]  = r;
    r = blockReduceSum((double)q7, sm4);  if (threadIdx.x == 0) p[7]  = r;
    r = blockReduceSum((double)q8, sm4);  if (threadIdx.x == 0) p[8]  = r;
    r = blockReduceSum((double)q9, sm4);  if (threadIdx.x == 0) p[9]  = r;
    r = blockReduceSum((double)q10, sm4); if (threadIdx.x == 0) p[10] = r;
}

// ---------------------------------------------------------------------------
// Combine per-block partials into acc[0..52]. 1 block x 256 threads.
// ---------------------------------------------------------------------------
__global__ __launch_bounds__(256) void k_combine(
    const double* __restrict__ part, double* __restrict__ acc)
{
    const int wave = threadIdx.x >> 6, lane = threadIdx.x & 63;
    for (int T = wave; T < 53; T += 4) {
        double v = 0.0;
        if (T < 48) {
            int g = T >> 3, bb = T & 7;
            int blk = bb * 256 + lane * 4;
#pragma unroll
            for (int i = 0; i < 4; ++i) v += part[(blk + i) * NPART + g];
        } else {
            int q = 6 + (T - 48);
#pragma unroll
            for (int i = 0; i < 32; ++i) v += part[(lane + 64 * i) * NPART + q];
        }
#pragma unroll
        for (int off = 32; off; off >>= 1) v += __shfl_down(v, off);
        if (lane == 0) {
            if (T < 48) acc[(T >> 3) * 8 + (T & 7)] = v;
            else        acc[48 + (T - 48)] = v;
        }
    }
}

// ---------------------------------------------------------------------------
// Final scalar combine.
// ---------------------------------------------------------------------------
__global__ void k_finalize(const double* __restrict__ acc, float* __restrict__ out)
{
    if (threadIdx.x != 0 || blockIdx.x != 0) return;
    const double eps = EPSV;
    const double Nd  = (double)N_ELEM;

    double dm = 0, ds = 0, cl = 0, msum = 0;
    for (int b = 0; b < BATCH; ++b) {
        dm += (2.0 * acc[0 + b] + eps) / (acc[8 + b] + acc[16 + b] + eps);
        ds += (2.0 * acc[24 + b] + eps) / (acc[32 + b] + acc[40 + b] + eps);
        double prec = acc[53 + b] / (acc[61 + b] + eps);
        double sens = acc[69 + b] / (acc[77 + b] + eps);
        cl += (2.0 * prec * sens + eps) / (prec + sens + eps);
        msum += acc[40 + b];
    }
    msum *= 2.0;   // skeleton mask broadcast over 2 affinity channels

    double mask_loss = (1.0 - dm / 8.0) + acc[48] / Nd;
    double skel_loss = 1.0 - ds / 8.0;
    double topo      = 1.0 - cl / 8.0;
    double node      = 0.5 * (acc[49] / Nd + acc[50] / Nd);
    double aff       = (msum == 0.0) ? 0.0 : acc[51] / fmax(msum, 1.0);
    double unc       = acc[52] / Nd;

    double total = mask_loss + skel_loss + 0.5 * topo + 0.5 * node + 0.5 * aff + 0.1 * unc;
    out[0] = (float)total;
}

// ---------------------------------------------------------------------------
extern "C" void kernel_launch(void* const* d_in, const int* in_sizes, int n_in,
                              void* d_out, int out_size, void* d_ws, size_t ws_size,
                              hipStream_t stream)
{
    const float* mask_logits = (const float*)d_in[0];
    const float* skel_logits = (const float*)d_in[1];
    const float* unc_logits  = (const float*)d_in[2];
    const float* junc_logits = (const float*)d_in[3];
    const float* endp_logits = (const float*)d_in[4];
    const float* aff_pred    = (const float*)d_in[5];
    const float* mask        = (const float*)d_in[6];
    const float* skel        = (const float*)d_in[7];
    const float* junc        = (const float*)d_in[8];
    const float* endp        = (const float*)d_in[9];
    const float* aff_tgt     = (const float*)d_in[10];
    const float* unc         = (const float*)d_in[11];
    float* out = (float*)d_out;

    char* ws = (char*)d_ws;
    double* acc  = (double*)ws;
    double* part = (double*)(ws + ACC_BYTES);
    float*  P1   = (float*)(ws + ACC_BYTES + MRB * NPART * sizeof(double)); // img_6
    float*  TBUF = P1 + NPIX_TOT;                                           // transparency t
    // ws usage: 1 KiB + 192 KiB + 16 MiB + 16 MiB ~= 33 MiB

    hipMemsetAsync(acc, 0, ACC_BYTES, stream);

    k_main_reduce<<<MRB, 256, 0, stream>>>(
        mask_logits, skel_logits, unc_logits, junc_logits, endp_logits,
        aff_pred, mask, skel, junc, endp, aff_tgt, unc, part);
    k_combine<<<1, 256, 0, stream>>>(part, acc);

    // Skeletonize: updates 0..5 then 6..10 (+ fused cldice reduce).
    k_skel_engine<6, 0><<<NCH * 32, 256, 0, stream>>>(
        mask_logits, mask, nullptr, nullptr, P1, TBUF, nullptr);
    k_skel_engine<5, 1><<<NCH * 32, 256, 0, stream>>>(
        P1, TBUF, mask_logits, mask, nullptr, nullptr, acc);

    k_finalize<<<1, 64, 0, stream>>>(acc, out);
}

// Round 6
// 230.360 us; speedup vs baseline: 2.1693x; 1.0588x over previous
//
#include <hip/hip_runtime.h>
#include <math.h>

// Problem geometry (fixed by the reference setup_inputs()).
#define HH 512
#define WW 512
#define BATCH 8
#define PIX (HH * WW)            // 262144 pixels per image
#define NCH 16                   // 8 pred + 8 target channels (fused skeletonize)
#define NPIX_TOT (NCH * PIX)
#define N_ELEM (BATCH * PIX)
#define EPSV 1e-6

// Accumulator layout (doubles at ws[0]):
//  [53..60] cldice sum ps*mask  [61..68] sum ps
//  [69..76] cldice sum ts*p     [77..84] sum ts   (written by engine MODE1)
#define ACC_COUNT 128
#define ACC_BYTES (ACC_COUNT * sizeof(double))
#define NPART 12
#define MRB 1024                 // main-reduce blocks

__device__ __forceinline__ float sigm(float x) {
    return __fdividef(1.0f, 1.0f + __expf(-x));
}
__device__ __forceinline__ float clamp01(float v) { return fminf(fmaxf(v, 0.0f), 1.0f); }

__device__ __forceinline__ float focal_term(float x, float t, float p) {
    float bce = fmaxf(x, 0.0f) - x * t - __logf(fmaxf(p, 1.0f - p));
    float p_t = p * t + (1.0f - p) * (1.0f - t);
    float a_t = 0.25f * t + 0.75f * (1.0f - t);
    float om  = 1.0f - p_t;
    return a_t * om * om * bce;
}

__device__ __forceinline__ double blockReduceSum(double v, double* sm4) {
    int lane = threadIdx.x & 63, wid = threadIdx.x >> 6;
#pragma unroll
    for (int off = 32; off; off >>= 1) v += __shfl_down(v, off);
    __syncthreads();
    if (lane == 0) sm4[wid] = v;
    __syncthreads();
    double r = 0.0;
    if (threadIdx.x == 0) r = sm4[0] + sm4[1] + sm4[2] + sm4[3];
    return r;
}

// ---------------------------------------------------------------------------
// float4 / 8-wide row helpers
// ---------------------------------------------------------------------------
struct F8 { float4 a, b; };

__device__ __forceinline__ float4 f4min(float4 x, float4 y) {
    return make_float4(fminf(x.x,y.x), fminf(x.y,y.y), fminf(x.z,y.z), fminf(x.w,y.w));
}
__device__ __forceinline__ float4 f4max(float4 x, float4 y) {
    return make_float4(fmaxf(x.x,y.x), fmaxf(x.y,y.y), fmaxf(x.z,y.z), fmaxf(x.w,y.w));
}
__device__ __forceinline__ F8 f8min(F8 x, F8 y) { F8 r; r.a=f4min(x.a,y.a); r.b=f4min(x.b,y.b); return r; }
__device__ __forceinline__ F8 f8max(F8 x, F8 y) { F8 r; r.a=f4max(x.a,y.a); r.b=f4max(x.b,y.b); return r; }
__device__ __forceinline__ F8 f8const(float v) {
    F8 r; r.a = make_float4(v,v,v,v); r.b = r.a; return r;
}
__device__ __forceinline__ F8 f8sigm(F8 x) {
    F8 r;
    r.a = make_float4(sigm(x.a.x), sigm(x.a.y), sigm(x.a.z), sigm(x.a.w));
    r.b = make_float4(sigm(x.b.x), sigm(x.b.y), sigm(x.b.z), sigm(x.b.w));
    return r;
}
__device__ __forceinline__ F8 f8clamp01(F8 x) {
    F8 r;
    r.a = make_float4(clamp01(x.a.x), clamp01(x.a.y), clamp01(x.a.z), clamp01(x.a.w));
    r.b = make_float4(clamp01(x.b.x), clamp01(x.b.y), clamp01(x.b.z), clamp01(x.b.w));
    return r;
}

// soft_erode on one row: min(center, up, down, left, right). Horizontal
// neighbors via in-register shifts + lane-edge shuffles (+inf at x-bounds).
__device__ __forceinline__ F8 erode_row(const F8& up, const F8& ce, const F8& dn, int lane) {
    F8 vm = f8min(f8min(up, dn), ce);
    float Lin = __shfl_up(ce.b.w, 1);
    float Rin = __shfl_down(ce.a.x, 1);
    if (lane == 0)  Lin = INFINITY;
    if (lane == 63) Rin = INFINITY;
    float4 la = make_float4(Lin,    ce.a.x, ce.a.y, ce.a.z);
    float4 lb = make_float4(ce.a.w, ce.b.x, ce.b.y, ce.b.z);
    float4 ra = make_float4(ce.a.y, ce.a.z, ce.a.w, ce.b.x);
    float4 rb = make_float4(ce.b.y, ce.b.z, ce.b.w, Rin);
    F8 r;
    r.a = f4min(vm.a, f4min(la, ra));
    r.b = f4min(vm.b, f4min(lb, rb));
    return r;
}

// 3x3 max of E at one row: separable (vertical max3 then horizontal max3,
// -inf at x-bounds).
__device__ __forceinline__ F8 max3_row(const F8& u, const F8& c, const F8& d, int lane) {
    F8 vm = f8max(f8max(u, d), c);
    float Lin = __shfl_up(vm.b.w, 1);
    float Rin = __shfl_down(vm.a.x, 1);
    if (lane == 0)  Lin = -INFINITY;
    if (lane == 63) Rin = -INFINITY;
    float4 la = make_float4(Lin,    vm.a.x, vm.a.y, vm.a.z);
    float4 lb = make_float4(vm.a.w, vm.b.x, vm.b.y, vm.b.z);
    float4 ra = make_float4(vm.a.y, vm.a.z, vm.a.w, vm.b.x);
    float4 rb = make_float4(vm.b.y, vm.b.z, vm.b.w, Rin);
    F8 r;
    r.a = f4max(vm.a, f4max(la, ra));
    r.b = f4max(vm.b, f4max(lb, rb));
    return r;
}

// t *= (1 - relu(img - mx))   [skel = 1 - t identity for the additive update]
__device__ __forceinline__ float4 f4updt(float4 t, float4 im, float4 mx) {
    return make_float4(t.x * (1.0f - fmaxf(im.x - mx.x, 0.0f)),
                       t.y * (1.0f - fmaxf(im.y - mx.y, 0.0f)),
                       t.z * (1.0f - fmaxf(im.z - mx.z, 0.0f)),
                       t.w * (1.0f - fmaxf(im.w - mx.w, 0.0f)));
}

// ---------------------------------------------------------------------------
// Row-register soft-skeletonize engine.
// Grid: 16 channels x 32 strips = 512 blocks x 256 threads (4 waves).
// Wave w holds rows [S-8+8w, S-8+8w+8); lane covers 8 px as two float4.
// Center waves (1,2) carry the t (transparency) state: skel = 1 - t.
// Halo exchange via DOUBLE-BUFFERED LDS: one barrier per iteration.
// Race-freedom: iteration it reads buf[it&1] after the barrier in it; the
// next write to that buffer (it+2) happens after the barrier in it+1, which
// globally follows all reads of it. Writes in it+1 target the other buffer.
// ---------------------------------------------------------------------------
template<int ITERS, int MODE>
__global__ __launch_bounds__(256, 2) void k_skel_engine(
    const float* __restrict__ srcA,   // MODE0: mask_logits ; MODE1: img buffer
    const float* __restrict__ srcB,   // MODE0: mask        ; MODE1: t buffer
    const float* __restrict__ mlg,    // MODE1: mask_logits (cldice, c>=8)
    const float* __restrict__ msk,    // MODE1: mask        (cldice, c<8)
    float* __restrict__ imgOut,       // MODE0
    float* __restrict__ tOut,         // MODE0
    double* __restrict__ acc)         // MODE1
{
    __shared__ float xbuf[2][4][4][WW];  // 64 KB, parity double-buffer
    __shared__ double sm4[4];

    const int tid   = threadIdx.x;
    const int lane  = tid & 63;
    const int w     = tid >> 6;
    const int c     = blockIdx.x >> 5;
    const int strip = blockIdx.x & 31;
    const int S     = strip * 16;
    const int grow0 = S - 8 + w * 8;
    const int x0    = lane * 8;
    const bool hasT = (w == 1 || w == 2);

    F8 img[8], t8[8];

    // ---- load held rows (+inf outside image) ----
#pragma unroll
    for (int j = 0; j < 8; ++j) {
        int g = grow0 + j;
        if (g < 0 || g >= HH) { img[j] = f8const(INFINITY); continue; }
        const float* base;
        if (MODE == 0) base = (c < 8) ? srcA + c * PIX : srcB + (c - 8) * PIX;
        else           base = srcA + c * PIX;
        const float* rp = base + (g << 9) + x0;
        F8 v; v.a = *(const float4*)rp; v.b = *(const float4*)(rp + 4);
        if (MODE == 0) v = (c < 8) ? f8sigm(v) : f8clamp01(v);
        img[j] = v;
    }
    if (MODE == 0) {
#pragma unroll
        for (int j = 0; j < 8; ++j) t8[j] = f8const(1.0f);
    } else {
        if (hasT) {
#pragma unroll
            for (int j = 0; j < 8; ++j) {
                const float* tp = srcB + c * PIX + ((grow0 + j) << 9) + x0;
                t8[j].a = *(const float4*)tp; t8[j].b = *(const float4*)(tp + 4);
            }
        } else {
#pragma unroll
            for (int j = 0; j < 8; ++j) t8[j] = f8const(1.0f);
        }
    }

    // ---- iterations ----
    for (int it = 0; it < ITERS; ++it) {
        const int pb = it & 1;
        *(float4*)&xbuf[pb][w][0][x0]     = img[0].a;
        *(float4*)&xbuf[pb][w][0][x0 + 4] = img[0].b;
        *(float4*)&xbuf[pb][w][1][x0]     = img[1].a;
        *(float4*)&xbuf[pb][w][1][x0 + 4] = img[1].b;
        *(float4*)&xbuf[pb][w][2][x0]     = img[6].a;
        *(float4*)&xbuf[pb][w][2][x0 + 4] = img[6].b;
        *(float4*)&xbuf[pb][w][3][x0]     = img[7].a;
        *(float4*)&xbuf[pb][w][3][x0 + 4] = img[7].b;
        __syncthreads();

        F8 hU0, hU1, hD0, hD1;
        if (w > 0) {
            hU0.a = *(float4*)&xbuf[pb][w-1][2][x0]; hU0.b = *(float4*)&xbuf[pb][w-1][2][x0 + 4];
            hU1.a = *(float4*)&xbuf[pb][w-1][3][x0]; hU1.b = *(float4*)&xbuf[pb][w-1][3][x0 + 4];
        } else { hU0 = f8const(INFINITY); hU1 = f8const(INFINITY); }
        if (w < 3) {
            hD0.a = *(float4*)&xbuf[pb][w+1][0][x0]; hD0.b = *(float4*)&xbuf[pb][w+1][0][x0 + 4];
            hD1.a = *(float4*)&xbuf[pb][w+1][1][x0]; hD1.b = *(float4*)&xbuf[pb][w+1][1][x0 + 4];
        } else { hD0 = f8const(INFINITY); hD1 = f8const(INFINITY); }

        // rolling erode window: Em1 = E[local j-1], E0 = E[j], Ep1 = E[j+1]
        F8 Em1 = erode_row(hU0, hU1, img[0], lane);
        { int g = grow0 - 1; if (g < 0 || g >= HH) Em1 = f8const(-INFINITY); }
        F8 E0  = erode_row(hU1, img[0], img[1], lane);
        { int g = grow0;     if (g < 0 || g >= HH) E0  = f8const(-INFINITY); }

#pragma unroll
        for (int j = 0; j < 8; ++j) {
            F8 ce = (j < 7) ? img[j + 1] : hD0;
            F8 dn = (j < 6) ? img[j + 2] : ((j == 6) ? hD0 : hD1);
            F8 Ep1 = erode_row(img[j], ce, dn, lane);
            { int g = grow0 + j + 1; if (g < 0 || g >= HH) Ep1 = f8const(-INFINITY); }
            if (hasT) {
                F8 mx = max3_row(Em1, E0, Ep1, lane);
                t8[j].a = f4updt(t8[j].a, img[j].a, mx.a);
                t8[j].b = f4updt(t8[j].b, img[j].b, mx.b);
            }
            img[j] = E0;          // img becomes eroded image for next iteration
            Em1 = E0; E0 = Ep1;
        }
    }

    // ---- epilogue ----
    if (MODE == 0) {
        if (hasT) {
#pragma unroll
            for (int j = 0; j < 8; ++j) {
                int g = grow0 + j;
                float* ip = imgOut + c * PIX + (g << 9) + x0;
                *(float4*)ip       = img[j].a;
                *(float4*)(ip + 4) = img[j].b;
                float* tp = tOut + c * PIX + (g << 9) + x0;
                *(float4*)tp       = t8[j].a;
                *(float4*)(tp + 4) = t8[j].b;
            }
        }
    } else {
        double s0 = 0.0, s1 = 0.0;
        if (hasT) {
#pragma unroll
            for (int j = 0; j < 8; ++j) {
                int g = grow0 + j;
                const float* op = (c < 8) ? (msk + c * PIX + (g << 9) + x0)
                                          : (mlg + (c - 8) * PIX + (g << 9) + x0);
                F8 o; o.a = *(const float4*)op; o.b = *(const float4*)(op + 4);
                if (c >= 8) o = f8sigm(o);
                float ps0 = clamp01(1.0f - t8[j].a.x), ps1 = clamp01(1.0f - t8[j].a.y);
                float ps2 = clamp01(1.0f - t8[j].a.z), ps3 = clamp01(1.0f - t8[j].a.w);
                float ps4 = clamp01(1.0f - t8[j].b.x), ps5 = clamp01(1.0f - t8[j].b.y);
                float ps6 = clamp01(1.0f - t8[j].b.z), ps7 = clamp01(1.0f - t8[j].b.w);
                float rs = ((ps0 + ps1) + (ps2 + ps3)) + ((ps4 + ps5) + (ps6 + ps7));
                float rp = ((ps0 * o.a.x + ps1 * o.a.y) + (ps2 * o.a.z + ps3 * o.a.w))
                         + ((ps4 * o.b.x + ps5 * o.b.y) + (ps6 * o.b.z + ps7 * o.b.w));
                s1 += (double)rs;
                s0 += (double)rp;
            }
        }
        __syncthreads();   // re-align waves before reduction LDS use
        double r0 = blockReduceSum(s0, sm4);
        double r1 = blockReduceSum(s1, sm4);
        if (tid == 0) {
            if (c < 8) { atomicAdd(&acc[53 + c], r0);     atomicAdd(&acc[61 + c], r1); }
            else       { atomicAdd(&acc[69 + c - 8], r0); atomicAdd(&acc[77 + c - 8], r1); }
        }
    }
}

// ---------------------------------------------------------------------------
// K1: point-wise losses. 1024 blocks, 8 px/thread (two float4 rounds).
// Tail: float butterfly per wave (no barriers), lane0 -> LDS, ONE barrier,
// 11 threads write the per-block partials as double.
// ---------------------------------------------------------------------------
__global__ __launch_bounds__(256) void k_main_reduce(
    const float* __restrict__ mask_logits, const float* __restrict__ skel_logits,
    const float* __restrict__ unc_logits,  const float* __restrict__ junc_logits,
    const float* __restrict__ endp_logits, const float* __restrict__ aff_pred,
    const float* __restrict__ mask,        const float* __restrict__ skel,
    const float* __restrict__ junc,        const float* __restrict__ endp,
    const float* __restrict__ aff_tgt,     const float* __restrict__ unc,
    double* __restrict__ part)
{
    __shared__ float smq[4][11];
    const int b    = blockIdx.x >> 7;
    const int pix0 = (blockIdx.x & 127) * 2048;

    float q[11];
#pragma unroll
    for (int i = 0; i < 11; ++i) q[i] = 0.0f;

#pragma unroll 1
    for (int r = 0; r < 2; ++r) {
        const int pix = pix0 + r * 1024 + threadIdx.x * 4;
        const int i   = b * PIX + pix;

        float4 ml = *(const float4*)&mask_logits[i];
        float4 mm = *(const float4*)&mask[i];
        float4 sl = *(const float4*)&skel_logits[i];
        float4 ss = *(const float4*)&skel[i];
        float4 jl = *(const float4*)&junc_logits[i];
        float4 jt = *(const float4*)&junc[i];
        float4 el = *(const float4*)&endp_logits[i];
        float4 et = *(const float4*)&endp[i];
        float4 ul = *(const float4*)&unc_logits[i];
        float4 ut = *(const float4*)&unc[i];
        float4 a0 = *(const float4*)&aff_pred[(b * 2 + 0) * PIX + pix];
        float4 t0 = *(const float4*)&aff_tgt [(b * 2 + 0) * PIX + pix];
        float4 a1 = *(const float4*)&aff_pred[(b * 2 + 1) * PIX + pix];
        float4 t1 = *(const float4*)&aff_tgt [(b * 2 + 1) * PIX + pix];

        const float* mlv = (const float*)&ml; const float* mmv = (const float*)&mm;
        const float* slv = (const float*)&sl; const float* ssv = (const float*)&ss;
        const float* jlv = (const float*)&jl; const float* jtv = (const float*)&jt;
        const float* elv = (const float*)&el; const float* etv = (const float*)&et;
        const float* ulv = (const float*)&ul; const float* utv = (const float*)&ut;
        const float* a0v = (const float*)&a0; const float* t0v = (const float*)&t0;
        const float* a1v = (const float*)&a1; const float* t1v = (const float*)&t1;

#pragma unroll
        for (int k = 0; k < 4; ++k) {
            float x = mlv[k], m = mmv[k];
            float p = sigm(x);
            q[0] += p * m; q[1] += p; q[2] += m;
            q[6] += focal_term(x, m, p);

            float sx = slv[k], s = ssv[k];
            float sp = sigm(sx);
            q[3] += sp * s; q[4] += sp; q[5] += s;

            float jx = jlv[k];
            q[7] += focal_term(jx, jtv[k], sigm(jx));
            float ex = elv[k];
            q[8] += focal_term(ex, etv[k], sigm(ex));

            float ud = sigm(ulv[k]) - utv[k];
            q[10] += ud * ud;

            float d0 = a0v[k] * s - t0v[k] * s;
            float ad0 = fabsf(d0);
            q[9] += (ad0 < 1.0f) ? 0.5f * d0 * d0 : ad0 - 0.5f;
            float d1 = a1v[k] * s - t1v[k] * s;
            float ad1 = fabsf(d1);
            q[9] += (ad1 < 1.0f) ? 0.5f * d1 * d1 : ad1 - 0.5f;
        }
    }

    // wave butterfly (float), no barriers
#pragma unroll
    for (int i = 0; i < 11; ++i) {
        float v = q[i];
        v += __shfl_xor(v, 1);  v += __shfl_xor(v, 2);  v += __shfl_xor(v, 4);
        v += __shfl_xor(v, 8);  v += __shfl_xor(v, 16); v += __shfl_xor(v, 32);
        q[i] = v;
    }
    const int lane = threadIdx.x & 63, wid = threadIdx.x >> 6;
    if (lane == 0) {
#pragma unroll
        for (int i = 0; i < 11; ++i) smq[wid][i] = q[i];
    }
    __syncthreads();
    if (threadIdx.x < 11) {
        double v = (double)smq[0][threadIdx.x] + (double)smq[1][threadIdx.x]
                 + (double)smq[2][threadIdx.x] + (double)smq[3][threadIdx.x];
        part[blockIdx.x * NPART + threadIdx.x] = v;
    }
}

// ---------------------------------------------------------------------------
// Combine partials + final scalar loss (one kernel, runs last).
// ---------------------------------------------------------------------------
__global__ __launch_bounds__(256) void k_finalize(
    const double* __restrict__ part, const double* __restrict__ acc,
    float* __restrict__ out)
{
    __shared__ double s[53];
    const int wave = threadIdx.x >> 6, lane = threadIdx.x & 63;
    for (int T = wave; T < 53; T += 4) {
        double v = 0.0;
        if (T < 48) {
            int g = T >> 3, bb = T & 7;
            int blk = bb * 128 + lane * 2;
            v = part[blk * NPART + g] + part[(blk + 1) * NPART + g];
        } else {
            int q = 6 + (T - 48);
#pragma unroll
            for (int i = 0; i < 16; ++i) v += part[(lane + 64 * i) * NPART + q];
        }
#pragma unroll
        for (int off = 32; off; off >>= 1) v += __shfl_down(v, off);
        if (lane == 0) s[T] = v;
    }
    __syncthreads();

    if (threadIdx.x != 0) return;
    const double eps = EPSV;
    const double Nd  = (double)N_ELEM;

    double dm = 0, ds = 0, cl = 0, msum = 0;
    for (int b = 0; b < BATCH; ++b) {
        dm += (2.0 * s[0 + b] + eps) / (s[8 + b] + s[16 + b] + eps);
        ds += (2.0 * s[24 + b] + eps) / (s[32 + b] + s[40 + b] + eps);
        double prec = acc[53 + b] / (acc[61 + b] + eps);
        double sens = acc[69 + b] / (acc[77 + b] + eps);
        cl += (2.0 * prec * sens + eps) / (prec + sens + eps);
        msum += s[40 + b];
    }
    msum *= 2.0;   // skeleton mask broadcast over 2 affinity channels

    double mask_loss = (1.0 - dm / 8.0) + s[48] / Nd;
    double skel_loss = 1.0 - ds / 8.0;
    double topo      = 1.0 - cl / 8.0;
    double node      = 0.5 * (s[49] / Nd + s[50] / Nd);
    double aff       = (msum == 0.0) ? 0.0 : s[51] / fmax(msum, 1.0);
    double unc       = s[52] / Nd;

    double total = mask_loss + skel_loss + 0.5 * topo + 0.5 * node + 0.5 * aff + 0.1 * unc;
    out[0] = (float)total;
}

// ---------------------------------------------------------------------------
extern "C" void kernel_launch(void* const* d_in, const int* in_sizes, int n_in,
                              void* d_out, int out_size, void* d_ws, size_t ws_size,
                              hipStream_t stream)
{
    const float* mask_logits = (const float*)d_in[0];
    const float* skel_logits = (const float*)d_in[1];
    const float* unc_logits  = (const float*)d_in[2];
    const float* junc_logits = (const float*)d_in[3];
    const float* endp_logits = (const float*)d_in[4];
    const float* aff_pred    = (const float*)d_in[5];
    const float* mask        = (const float*)d_in[6];
    const float* skel        = (const float*)d_in[7];
    const float* junc        = (const float*)d_in[8];
    const float* endp        = (const float*)d_in[9];
    const float* aff_tgt     = (const float*)d_in[10];
    const float* unc         = (const float*)d_in[11];
    float* out = (float*)d_out;

    char* ws = (char*)d_ws;
    double* acc  = (double*)ws;
    double* part = (double*)(ws + ACC_BYTES);
    float*  P1   = (float*)(ws + ACC_BYTES + MRB * NPART * sizeof(double)); // img_6
    float*  TBUF = P1 + NPIX_TOT;                                           // transparency t
    // ws usage: 1 KiB + 96 KiB + 16 MiB + 16 MiB ~= 33 MiB

    hipMemsetAsync(acc, 0, ACC_BYTES, stream);   // zeroes cldice atomics' targets

    k_main_reduce<<<MRB, 256, 0, stream>>>(
        mask_logits, skel_logits, unc_logits, junc_logits, endp_logits,
        aff_pred, mask, skel, junc, endp, aff_tgt, unc, part);

    // Skeletonize: updates 0..5 then 6..10 (+ fused cldice reduce).
    k_skel_engine<6, 0><<<NCH * 32, 256, 0, stream>>>(
        mask_logits, mask, nullptr, nullptr, P1, TBUF, nullptr);
    k_skel_engine<5, 1><<<NCH * 32, 256, 0, stream>>>(
        P1, TBUF, mask_logits, mask, nullptr, nullptr, acc);

    k_finalize<<<1, 256, 0, stream>>>(part, acc, out);
}